// Round 7
// baseline (104.624 us; speedup 1.0000x reference)
//
#include <hip/hip_runtime.h>
#include <hip/hip_bf16.h>
#include <stdint.h>

#define B_ 4
#define S_ 2048
#define D_ 512
#define H_ 8

typedef __attribute__((ext_vector_type(4))) float f32x4;
typedef __attribute__((ext_vector_type(16))) float f32x16;
typedef __attribute__((ext_vector_type(8))) short s16x8;

__device__ __forceinline__ unsigned short f2bf(float x) {
  union { float f; unsigned u; } v; v.f = x;
  unsigned r = v.u + 0x7FFFu + ((v.u >> 16) & 1u);
  return (unsigned short)(r >> 16);
}

__device__ __forceinline__ unsigned cvtpk_bf16(float lo, float hi) {
  unsigned r;
  asm("v_cvt_pk_bf16_f32 %0, %1, %2" : "=v"(r) : "v"(lo), "v"(hi));
  return r;
}

// v_permlane32_swap_b32: a <- {a.lo, b.lo}, b <- {a.hi, b.hi} (lane halves)
__device__ __forceinline__ void plswap(unsigned &a, unsigned &b) {
  asm("v_permlane32_swap_b32 %0, %1" : "+v"(a), "+v"(b));
}

__device__ __forceinline__ float fexp2(float x) {
  float r;
  asm("v_exp_f32 %0, %1" : "=v"(r) : "v"(x));
  return r;
}

__device__ __forceinline__ void gload16(const void* g, void* lds) {
  __builtin_amdgcn_global_load_lds(
      (const __attribute__((address_space(1))) void*)g,
      (__attribute__((address_space(3))) void*)lds, 16, 0, 0);
}

// ---------------------------------------------------------------------------
// conv_kv: Kbf[bh][s][dh] = bf16(K); Vt[bh][dh][s] = bf16(V * cutoff * mask);
// fmgf[b][s] = mask ? 1.0f : 0.0f.  grid (S/64, B*H), 256 threads.
// ---------------------------------------------------------------------------
__global__ __launch_bounds__(256) void conv_kv_kernel(
    const float* __restrict__ km, const float* __restrict__ vm,
    const float* __restrict__ cut, const int* __restrict__ mask,
    unsigned short* __restrict__ Kbf, unsigned short* __restrict__ Vt,
    float* __restrict__ fmgf)
{
  const int st = blockIdx.x, bh = blockIdx.y;
  const int b = bh >> 3, h = bh & 7;
  const int s0 = st * 64;
  __shared__ unsigned short sT[64][68];
  const int tid = threadIdx.x;
#pragma unroll
  for (int j = 0; j < 4; ++j) {
    const int li = tid + j * 256;
    const int r  = li >> 4;
    const int c4 = (li & 15) * 4;
    const size_t g = ((size_t)(b * S_ + s0 + r)) * D_ + h * 64 + c4;
    const float4 kv = *(const float4*)(km + g);
    const float4 vv = *(const float4*)(vm + g);
    const int mk = mask[(size_t)b * S_ + s0 + r];
    const float f = mk ? cut[(size_t)b * S_ + s0 + r] : 0.f;
    *(ushort4*)(Kbf + ((size_t)(bh * S_ + s0 + r)) * 64 + c4) =
        make_ushort4(f2bf(kv.x), f2bf(kv.y), f2bf(kv.z), f2bf(kv.w));
    sT[r][c4 + 0] = f2bf(vv.x * f);
    sT[r][c4 + 1] = f2bf(vv.y * f);
    sT[r][c4 + 2] = f2bf(vv.z * f);
    sT[r][c4 + 3] = f2bf(vv.w * f);
    if (h == 0 && c4 == 0)
      fmgf[(size_t)b * S_ + s0 + r] = mk ? 1.0f : 0.0f;
  }
  __syncthreads();
#pragma unroll
  for (int j = 0; j < 4; ++j) {
    const int li = tid + j * 256;
    const int dh = li >> 4;
    const int s4 = (li & 15) * 4;
    *(ushort4*)(Vt + ((size_t)(bh * 64 + dh)) * S_ + s0 + s4) =
        make_ushort4(sT[s4 + 0][dh], sT[s4 + 1][dh], sT[s4 + 2][dh], sT[s4 + 3][dh]);
  }
}

// ---------------------------------------------------------------------------
// conv_w: Wt[n][k] = bf16(W[k][n]).  grid (8, 8), 256 threads
// ---------------------------------------------------------------------------
__global__ __launch_bounds__(256) void conv_w_kernel(
    const float* __restrict__ W, unsigned short* __restrict__ Wt)
{
  const int k0 = blockIdx.x * 64, n0 = blockIdx.y * 64;
  __shared__ unsigned short sT[64][68];
  const int tid = threadIdx.x;
#pragma unroll
  for (int j = 0; j < 4; ++j) {
    const int li = tid + j * 256;
    const int r  = li >> 4;
    const int c4 = (li & 15) * 4;
    const float4 wv = *(const float4*)(W + (size_t)(k0 + r) * 512 + n0 + c4);
    sT[r][c4 + 0] = f2bf(wv.x);
    sT[r][c4 + 1] = f2bf(wv.y);
    sT[r][c4 + 2] = f2bf(wv.z);
    sT[r][c4 + 3] = f2bf(wv.w);
  }
  __syncthreads();
#pragma unroll
  for (int j = 0; j < 4; ++j) {
    const int li = tid + j * 256;
    const int n  = li >> 4;
    const int k4 = (li & 15) * 4;
    *(ushort4*)(Wt + (size_t)(n0 + n) * 512 + k0 + k4) =
        make_ushort4(sT[k4 + 0][n], sT[k4 + 1][n], sT[k4 + 2][n], sT[k4 + 3][n]);
  }
}

// ---------------------------------------------------------------------------
// attn: swapped-QK^T, 32x32x16 bf16 MFMA, no max tracking, VALU denominator.
// grid (S/64, B*H) = 1024 blocks, 256 threads = 4 waves (qh = w&1, kh = w>>1).
// Round-5-PROVEN staging template: stage next tile into the OTHER buffer at
// the top of each iteration, ONE __syncthreads at the end. Asymmetric tiles:
// K double-buffered at 32 keys (16 KB), V double-buffered at 64 keys (32 KB,
// staged every other iteration). 48 KB LDS -> 3 blocks/CU.
// Additive (O,l) partials merged 2-way (kh) through LDS in two passes.
// ---------------------------------------------------------------------------
__global__ __launch_bounds__(256, 3) void attn_mfma_kernel(
    const float* __restrict__ qv, const unsigned short* __restrict__ Kbf,
    const unsigned short* __restrict__ Vt, const float* __restrict__ fmgf,
    unsigned short* __restrict__ attb)
{
  __shared__ unsigned short sK[2][2][2048];   // [kh][buf][key32][dh64] 16 KB
  __shared__ unsigned short sV[2][2][4096];   // [kh][buf][dh64][key64] 32 KB

  const int qt = blockIdx.x, bh = blockIdx.y;
  const int b = bh >> 3, h = bh & 7;
  const int tid = threadIdx.x, w = tid >> 6, l = tid & 63;
  const int l31 = l & 31, hi = l >> 5;
  const int qh = w & 1, kh = w >> 1;
  const int kbase = kh * 1024;

  // Q B-fragment (32 q-rows), scale = 1/8 * log2(e) folded in (exp -> exp2)
  s16x8 qf[4];
  {
    const float QS = 0.125f * 1.44269504088896f;
    const int qrow = qt * 64 + qh * 32 + l31;
    const float* qp = qv + ((size_t)(b * S_ + qrow)) * D_ + h * 64 + hi * 8;
#pragma unroll
    for (int kc = 0; kc < 4; ++kc) {
      const float4 a0 = *(const float4*)(qp + kc * 16);
      const float4 a1 = *(const float4*)(qp + kc * 16 + 4);
      union { unsigned u[4]; s16x8 v; } t;
      t.u[0] = cvtpk_bf16(a0.x * QS, a0.y * QS);
      t.u[1] = cvtpk_bf16(a0.z * QS, a0.w * QS);
      t.u[2] = cvtpk_bf16(a1.x * QS, a1.y * QS);
      t.u[3] = cvtpk_bf16(a1.z * QS, a1.w * QS);
      qf[kc] = t.v;
    }
  }

  f32x16 o0, o1;
  float lsum = 0.f;
#pragma unroll
  for (int r = 0; r < 16; ++r) { o0[r] = 0.f; o1[r] = 0.f; }

  const int swl = ((l & 7) ^ (l >> 3)) * 16;
  const int r8  = l >> 3;
  const char* KbfB = (const char*)(Kbf + (size_t)bh * S_ * 64);
  const char* VtB  = (const char*)(Vt + (size_t)bh * 64 * S_);
  const float* fmB = fmgf + (size_t)b * S_;

  // K subtile kt (32 keys) -> sK[kh][bufi]; 2 waves/kh pair, 2 chunks each
  auto STAGE_K = [&](int kt, int bufi) {
    const int k0 = kbase + kt * 32;
#pragma unroll
    for (int c = 0; c < 2; ++c) {
      const int chunk = qh * 2 + c;           // 0..3
      const int row = chunk * 8 + r8;         // 0..31
      gload16(KbfB + (size_t)(k0 + row) * 128 + swl,
              (char*)sK[kh][bufi] + chunk * 1024);
    }
  };
  // V tile vt (64 keys) -> sV[kh][bufi]; 2 waves/kh pair, 4 chunks each
  auto STAGE_V = [&](int vt, int bufi) {
    const int k0 = kbase + vt * 64;
#pragma unroll
    for (int c = 0; c < 4; ++c) {
      const int chunk = qh * 4 + c;           // 0..7
      const int row = chunk * 8 + r8;         // dh 0..63
      gload16(VtB + ((size_t)row * S_ + k0) * 2 + swl,
              (char*)sV[kh][bufi] + chunk * 1024);
    }
  };

  STAGE_K(0, 0);
  STAGE_V(0, 0);
  __syncthreads();

  int kb = 0, vbuf = 0;
  for (int kt = 0; kt < 32; ++kt) {
    const int half = kt & 1, vt = kt >> 1;
    // stage next tiles into the OTHER buffers (proven template)
    if (kt + 1 < 32) STAGE_K(kt + 1, kb ^ 1);
    if (half == 1 && vt + 1 < 16) STAGE_V(vt + 1, vbuf ^ 1);

    const char* pK = (const char*)sK[kh][kb];
    const char* pV = (const char*)sV[kh][vbuf];

    // QK^T for this 32-key subtile (rows = keys = l31)
    f32x16 sa;
#pragma unroll
    for (int r = 0; r < 16; ++r) sa[r] = 0.f;
    __builtin_amdgcn_s_setprio(1);
#pragma unroll
    for (int kc = 0; kc < 4; ++kc) {
      const s16x8 kf = *(const s16x8*)(pK + l31 * 128 +
                        ((kc * 32 + hi * 16) ^ ((l31 & 7) << 4)));
      sa = __builtin_amdgcn_mfma_f32_32x32x16_bf16(kf, qf[kc], sa, 0, 0, 0);
    }
    __builtin_amdgcn_s_setprio(0);

    // p = exp2(s2); denominator via VALU fmac against f32 mask
    const int kg0 = kbase + kt * 32;
    float4 fm4[4];
#pragma unroll
    for (int j = 0; j < 4; ++j)
      fm4[j] = *(const float4*)(fmB + kg0 + j * 8 + hi * 4);
    float p[16];
#pragma unroll
    for (int r = 0; r < 16; ++r) p[r] = fexp2(sa[r]);
#pragma unroll
    for (int j = 0; j < 4; ++j) {
      lsum = fmaf(p[j * 4 + 0], fm4[j].x, lsum);
      lsum = fmaf(p[j * 4 + 1], fm4[j].y, lsum);
      lsum = fmaf(p[j * 4 + 2], fm4[j].z, lsum);
      lsum = fmaf(p[j * 4 + 3], fm4[j].w, lsum);
    }

    // pack P -> A fragments (2 slices of 16 keys)
    s16x8 pa[2];
#pragma unroll
    for (int ks = 0; ks < 2; ++ks) {
      const int rb = ks * 8;
      unsigned a0 = cvtpk_bf16(p[rb + 0], p[rb + 1]);
      unsigned a1 = cvtpk_bf16(p[rb + 2], p[rb + 3]);
      unsigned b0 = cvtpk_bf16(p[rb + 4], p[rb + 5]);
      unsigned b1 = cvtpk_bf16(p[rb + 6], p[rb + 7]);
      plswap(a0, b0); plswap(a1, b1);
      union { unsigned u[4]; s16x8 v; } t;
      t.u[0] = a0; t.u[1] = a1; t.u[2] = b0; t.u[3] = b1;
      pa[ks] = t.v;
    }

    // PV: keys of this subtile sit at offset half*32 within the 64-key V tile
    __builtin_amdgcn_s_setprio(1);
#pragma unroll
    for (int ks = 0; ks < 2; ++ks) {
      const int cb = (half * 2 + ks) * 32 + hi * 16;
      const int rv0 = l31, rv1 = 32 + l31;
      const s16x8 vb0 = *(const s16x8*)(pV + rv0 * 128 + (cb ^ ((rv0 & 7) << 4)));
      const s16x8 vb1 = *(const s16x8*)(pV + rv1 * 128 + (cb ^ ((rv1 & 7) << 4)));
      o0 = __builtin_amdgcn_mfma_f32_32x32x16_bf16(pa[ks], vb0, o0, 0, 0, 0);
      o1 = __builtin_amdgcn_mfma_f32_32x32x16_bf16(pa[ks], vb1, o1, 0, 0, 0);
    }
    __builtin_amdgcn_s_setprio(0);

    __syncthreads();   // single barrier per iteration (drains staged loads)
    kb ^= 1;
    vbuf ^= half;
  }

  // total l per query (both hi halves)
  const float lt = lsum + __shfl_xor(lsum, 32);

  // ---- 2-way kh merge through LDS, two passes ----
  float* po = (float*)&sK[0][0][0];  // [qh][half][r][lane] = 4096 f32 = 16 KB
  float* pl = (float*)&sV[0][0][0];  // [qh*32 + q] = 64 f32

  if (kh == 0) {
#pragma unroll
    for (int r = 0; r < 16; ++r) {
      po[((qh * 2 + 0) * 16 + r) * 64 + l] = o0[r];
      po[((qh * 2 + 1) * 16 + r) * 64 + l] = o1[r];
    }
    if (hi == 0) pl[qh * 32 + l31] = lt;
  }
  __syncthreads();
  if (kh == 1) {
#pragma unroll
    for (int r = 0; r < 16; ++r) {
      po[((qh * 2 + 0) * 16 + r) * 64 + l] += o0[r];
      po[((qh * 2 + 1) * 16 + r) * 64 + l] += o1[r];
    }
    if (hi == 0) pl[qh * 32 + l31] += lt;
  }
  __syncthreads();

  // output: wave w -> (qh_o = w&1, dh-half sm = w>>1)
  const int qh_o = w & 1, sm = w >> 1;
  unsigned short* ob = attb + ((size_t)b * S_) * D_ + h * 64;
#pragma unroll
  for (int r = 0; r < 16; ++r) {
    const int qloc = (r & 3) + 8 * (r >> 2) + 4 * hi;
    const float inv = 1.f / pl[qh_o * 32 + qloc];
    const float ov = po[((qh_o * 2 + sm) * 16 + r) * 64 + l];
    const int q = qt * 64 + qh_o * 32 + qloc;
    ob[(size_t)q * D_ + sm * 32 + l31] = f2bf(ov * inv);
  }
}

// ---------------------------------------------------------------------------
// proj: out[8192,512] = attb(bf16) @ W via Wt[n][k], MFMA, 128x128 tiles.
// ---------------------------------------------------------------------------
__global__ __launch_bounds__(256) void proj_mfma_kernel(
    const unsigned short* __restrict__ A, const unsigned short* __restrict__ Wt,
    float* __restrict__ out)
{
  __shared__ unsigned short sA[128 * 64];
  __shared__ unsigned short sB[128 * 64];
  const int m0 = blockIdx.x * 128, n0 = blockIdx.y * 128;
  const int tid = threadIdx.x, w = tid >> 6, l = tid & 63;
  const int l15 = l & 15, l4 = l >> 4;
  const int wm = (w >> 1) * 64, wn = (w & 1) * 64;
  const int swl = ((l & 7) ^ (l >> 3)) * 16;
  const int r8 = l >> 3;

  f32x4 acc[4][4];
#pragma unroll
  for (int i = 0; i < 4; ++i)
#pragma unroll
    for (int j = 0; j < 4; ++j) acc[i][j] = (f32x4){0.f, 0.f, 0.f, 0.f};

  for (int kt = 0; kt < 8; ++kt) {
    const int k0 = kt * 64;
    __syncthreads();
#pragma unroll
    for (int c = 0; c < 4; ++c) {
      const int chunk = w * 4 + c;
      const int r = chunk * 8 + r8;
      gload16((const char*)(A + ((size_t)(m0 + r)) * 512 + k0) + swl,
              (char*)sA + chunk * 1024);
      gload16((const char*)(Wt + ((size_t)(n0 + r)) * 512 + k0) + swl,
              (char*)sB + chunk * 1024);
    }
    __syncthreads();
#pragma unroll
    for (int ks = 0; ks < 2; ++ks) {
      s16x8 af[4], bf_[4];
#pragma unroll
      for (int mb = 0; mb < 4; ++mb) {
        const int row = wm + mb * 16 + l15;
        const int sz = (row & 7) << 4;
        af[mb] = *(const s16x8*)((const char*)sA + row * 128 + ((ks * 64 + l4 * 16) ^ sz));
      }
#pragma unroll
      for (int nb = 0; nb < 4; ++nb) {
        const int row = wn + nb * 16 + l15;
        const int sz = (row & 7) << 4;
        bf_[nb] = *(const s16x8*)((const char*)sB + row * 128 + ((ks * 64 + l4 * 16) ^ sz));
      }
#pragma unroll
      for (int mb = 0; mb < 4; ++mb)
#pragma unroll
        for (int nb = 0; nb < 4; ++nb)
          acc[mb][nb] = __builtin_amdgcn_mfma_f32_16x16x32_bf16(af[mb], bf_[nb], acc[mb][nb], 0, 0, 0);
    }
  }
#pragma unroll
  for (int mb = 0; mb < 4; ++mb)
#pragma unroll
    for (int nb = 0; nb < 4; ++nb)
#pragma unroll
      for (int r = 0; r < 4; ++r)
        out[(size_t)(m0 + wm + mb * 16 + l4 * 4 + r) * 512 + n0 + wn + nb * 16 + l15] =
            acc[mb][nb][r];
}

extern "C" void kernel_launch(void* const* d_in, const int* in_sizes, int n_in,
                              void* d_out, int out_size, void* d_ws, size_t ws_size,
                              hipStream_t stream) {
  const float* q    = (const float*)d_in[0];
  const float* k    = (const float*)d_in[1];
  const float* v    = (const float*)d_in[2];
  const int*   mask = (const int*)d_in[3];
  const float* cut  = (const float*)d_in[4];
  const float* W    = (const float*)d_in[5];
  float* out = (float*)d_out;

  char* ws = (char*)d_ws;
  unsigned short* Kbf  = (unsigned short*)(ws);                    // 8 MB
  unsigned short* Vt   = (unsigned short*)(ws + (8u << 20));       // 8 MB
  unsigned short* attb = (unsigned short*)(ws + (16u << 20));      // 8 MB
  unsigned short* Wt   = (unsigned short*)(ws + (24u << 20));      // 0.5 MB
  float*          fmgf = (float*)(ws + (25u << 20));               // 32 KB

  conv_kv_kernel<<<dim3(S_ / 64, B_ * H_), 256, 0, stream>>>(k, v, cut, mask, Kbf, Vt, fmgf);
  conv_w_kernel<<<dim3(8, 8), 256, 0, stream>>>(W, Wt);
  attn_mfma_kernel<<<dim3(S_ / 64, B_ * H_), 256, 0, stream>>>(q, Kbf, Vt, fmgf, attb);
  proj_mfma_kernel<<<dim3(64, 4), 256, 0, stream>>>(attb, Wt, out);
}

// Round 12
// 92.815 us; speedup vs baseline: 1.1272x; 1.1272x over previous
//
#include <hip/hip_runtime.h>
#include <hip/hip_bf16.h>
#include <stdint.h>

#define B_ 4
#define S_ 2048
#define D_ 512
#define H_ 8

typedef __attribute__((ext_vector_type(4))) float f32x4;
typedef __attribute__((ext_vector_type(16))) float f32x16;
typedef __attribute__((ext_vector_type(8))) short s16x8;

__device__ __forceinline__ unsigned short f2bf(float x) {
  union { float f; unsigned u; } v; v.f = x;
  unsigned r = v.u + 0x7FFFu + ((v.u >> 16) & 1u);
  return (unsigned short)(r >> 16);
}

__device__ __forceinline__ unsigned cvtpk_bf16(float lo, float hi) {
  unsigned r;
  asm("v_cvt_pk_bf16_f32 %0, %1, %2" : "=v"(r) : "v"(lo), "v"(hi));
  return r;
}

// v_permlane32_swap_b32: a <- {a.lo, b.lo}, b <- {a.hi, b.hi}
__device__ __forceinline__ void plswap(unsigned &a, unsigned &b) {
  asm("v_permlane32_swap_b32 %0, %1" : "+v"(a), "+v"(b));
}

__device__ __forceinline__ void gload16(const void* g, void* lds) {
  __builtin_amdgcn_global_load_lds(
      (const __attribute__((address_space(1))) void*)g,
      (__attribute__((address_space(3))) void*)lds, 16, 0, 0);
}

// ---------------------------------------------------------------------------
// conv_kv: Kbf[bh][s][dh] = bf16(K); Vt[bh][dh][s] = bf16(V * cutoff * mask);
// fmg[b][s] = bf16(mask ? 1 : 0).  grid (S/64, B*H), 256 threads.
// (EXACT round-5 version.)
// ---------------------------------------------------------------------------
__global__ __launch_bounds__(256) void conv_kv_kernel(
    const float* __restrict__ km, const float* __restrict__ vm,
    const float* __restrict__ cut, const int* __restrict__ mask,
    unsigned short* __restrict__ Kbf, unsigned short* __restrict__ Vt,
    unsigned short* __restrict__ fmg)
{
  const int st = blockIdx.x, bh = blockIdx.y;
  const int b = bh >> 3, h = bh & 7;
  const int s0 = st * 64;
  __shared__ unsigned short sT[64][68];
  const int tid = threadIdx.x;
#pragma unroll
  for (int j = 0; j < 4; ++j) {
    const int li = tid + j * 256;
    const int r  = li >> 4;
    const int c4 = (li & 15) * 4;
    const size_t g = ((size_t)(b * S_ + s0 + r)) * D_ + h * 64 + c4;
    const float4 kv = *(const float4*)(km + g);
    const float4 vv = *(const float4*)(vm + g);
    const int mk = mask[(size_t)b * S_ + s0 + r];
    const float f = mk ? cut[(size_t)b * S_ + s0 + r] : 0.f;
    *(ushort4*)(Kbf + ((size_t)(bh * S_ + s0 + r)) * 64 + c4) =
        make_ushort4(f2bf(kv.x), f2bf(kv.y), f2bf(kv.z), f2bf(kv.w));
    sT[r][c4 + 0] = f2bf(vv.x * f);
    sT[r][c4 + 1] = f2bf(vv.y * f);
    sT[r][c4 + 2] = f2bf(vv.z * f);
    sT[r][c4 + 3] = f2bf(vv.w * f);
    if (h == 0 && c4 == 0)
      fmg[(size_t)b * S_ + s0 + r] = mk ? (unsigned short)0x3F80 : (unsigned short)0;
  }
  __syncthreads();
#pragma unroll
  for (int j = 0; j < 4; ++j) {
    const int li = tid + j * 256;
    const int dh = li >> 4;
    const int s4 = (li & 15) * 4;
    *(ushort4*)(Vt + ((size_t)(bh * 64 + dh)) * S_ + s0 + s4) =
        make_ushort4(sT[s4 + 0][dh], sT[s4 + 1][dh], sT[s4 + 2][dh], sT[s4 + 3][dh]);
  }
}

// ---------------------------------------------------------------------------
// conv_w: Wt[n][k] = bf16(W[k][n]).  grid (8, 8), 256 threads
// ---------------------------------------------------------------------------
__global__ __launch_bounds__(256) void conv_w_kernel(
    const float* __restrict__ W, unsigned short* __restrict__ Wt)
{
  const int k0 = blockIdx.x * 64, n0 = blockIdx.y * 64;
  __shared__ unsigned short sT[64][68];
  const int tid = threadIdx.x;
#pragma unroll
  for (int j = 0; j < 4; ++j) {
    const int li = tid + j * 256;
    const int r  = li >> 4;
    const int c4 = (li & 15) * 4;
    const float4 wv = *(const float4*)(W + (size_t)(k0 + r) * 512 + n0 + c4);
    sT[r][c4 + 0] = f2bf(wv.x);
    sT[r][c4 + 1] = f2bf(wv.y);
    sT[r][c4 + 2] = f2bf(wv.z);
    sT[r][c4 + 3] = f2bf(wv.w);
  }
  __syncthreads();
#pragma unroll
  for (int j = 0; j < 4; ++j) {
    const int li = tid + j * 256;
    const int n  = li >> 4;
    const int k4 = (li & 15) * 4;
    *(ushort4*)(Wt + (size_t)(n0 + n) * 512 + k0 + k4) =
        make_ushort4(sT[k4 + 0][n], sT[k4 + 1][n], sT[k4 + 2][n], sT[k4 + 3][n]);
  }
}

// ---------------------------------------------------------------------------
// attn: EXACT round-5 kernel (passed, 59.4us) with ONE delta: p = exp2f(s)
// (standard HIP intrinsic, compiler-visible v_exp_f32 with hazard handling —
// NOT inline asm) with 1/8*log2(e) folded into Q. Denominator stays la-MFMA.
// grid (S/128, B*H), 256 threads = 4 waves. Wave w = (qh = w&1, kh = w>>1):
// owns 64 q-rows (2 MFMA streams) and 1024 keys (16 tiles of 64).
// Additive (O,l) partials merged 2-way through LDS in TWO PASSES.
// ---------------------------------------------------------------------------
__global__ __launch_bounds__(256, 2) void attn_mfma_kernel(
    const float* __restrict__ qv, const unsigned short* __restrict__ Kbf,
    const unsigned short* __restrict__ Vt, const unsigned short* __restrict__ fmg,
    unsigned short* __restrict__ attb)
{
  __shared__ unsigned short sK[2][2][4096];   // [kh][buf][key][dh] swizzled, 32 KB
  __shared__ unsigned short sV[2][2][4096];   // [kh][buf][dh][key] swizzled, 32 KB

  const int qt = blockIdx.x, bh = blockIdx.y;
  const int b = bh >> 3, h = bh & 7;
  const int tid = threadIdx.x, w = tid >> 6, l = tid & 63;
  const int l31 = l & 31, hi = l >> 5;
  const int qh = w & 1, kh = w >> 1;
  const int kbase = kh * 1024;

  // Q B-fragments, 2 streams of 32 q-rows, 1/8 * log2(e) folded in
  s16x8 qf[2][4];
#pragma unroll
  for (int s = 0; s < 2; ++s) {
    const float QS = 0.125f * 1.44269504088896f;
    const int qrow = qt * 128 + qh * 64 + s * 32 + l31;
    const float* qp = qv + ((size_t)(b * S_ + qrow)) * D_ + h * 64 + hi * 8;
#pragma unroll
    for (int kc = 0; kc < 4; ++kc) {
      const float4 a0 = *(const float4*)(qp + kc * 16);
      const float4 a1 = *(const float4*)(qp + kc * 16 + 4);
      union { unsigned u[4]; s16x8 v; } t;
      t.u[0] = cvtpk_bf16(a0.x * QS, a0.y * QS);
      t.u[1] = cvtpk_bf16(a0.z * QS, a0.w * QS);
      t.u[2] = cvtpk_bf16(a1.x * QS, a1.y * QS);
      t.u[3] = cvtpk_bf16(a1.z * QS, a1.w * QS);
      qf[s][kc] = t.v;
    }
  }

  f32x16 o00, o01, o10, o11, la0, la1;
#pragma unroll
  for (int r = 0; r < 16; ++r) {
    o00[r] = 0.f; o01[r] = 0.f; o10[r] = 0.f; o11[r] = 0.f;
    la0[r] = 0.f; la1[r] = 0.f;
  }

  const int swl = ((l & 7) ^ (l >> 3)) * 16;
  const int r8  = l >> 3;
  const char* KbfB = (const char*)(Kbf + (size_t)bh * S_ * 64);
  const char* VtB  = (const char*)(Vt + (size_t)bh * 64 * S_);

  auto STAGE = [&](int bufi, int kt) {
    const int k0 = kbase + kt * 64;
#pragma unroll
    for (int c = 0; c < 4; ++c) {
      const int chunk = qh * 4 + c;          // pair {qh=0,qh=1} covers chunks 0..7
      const int row = chunk * 8 + r8;
      gload16(KbfB + (size_t)(k0 + row) * 128 + swl, (char*)sK[kh][bufi] + chunk * 1024);
      gload16(VtB + ((size_t)row * S_ + k0) * 2 + swl, (char*)sV[kh][bufi] + chunk * 1024);
    }
  };

  STAGE(0, 0);
  __syncthreads();

  int buf = 0;
  for (int kt = 0; kt < 16; ++kt) {
    const int k0 = kbase + kt * 64;
    // fmask fragments for this tile (direct from global, L1-broadcast)
    s16x8 fmf[4];
#pragma unroll
    for (int ks = 0; ks < 4; ++ks)
      fmf[ks] = *(const s16x8*)(fmg + (size_t)b * S_ + k0 + ks * 16 + hi * 8);

    if (kt + 1 < 16) STAGE(buf ^ 1, kt + 1);

    const char* pK = (const char*)sK[kh][buf];
    const char* pV = (const char*)sV[kh][buf];

    // QK^T per 32-key half; p = exp2(s); pack to bf16 A-fragments in-register
    s16x8 pa[2][4];
#pragma unroll
    for (int k2 = 0; k2 < 2; ++k2) {
      f32x16 sa0, sa1;
#pragma unroll
      for (int r = 0; r < 16; ++r) { sa0[r] = 0.f; sa1[r] = 0.f; }
      __builtin_amdgcn_s_setprio(1);
#pragma unroll
      for (int kc = 0; kc < 4; ++kc) {
        const int row = k2 * 32 + l31;
        const s16x8 kf = *(const s16x8*)(pK + row * 128 +
                          ((kc * 32 + hi * 16) ^ ((row & 7) << 4)));
        sa0 = __builtin_amdgcn_mfma_f32_32x32x16_bf16(kf, qf[0][kc], sa0, 0, 0, 0);
        sa1 = __builtin_amdgcn_mfma_f32_32x32x16_bf16(kf, qf[1][kc], sa1, 0, 0, 0);
      }
      __builtin_amdgcn_s_setprio(0);
      float p0[16], p1[16];
#pragma unroll
      for (int r = 0; r < 16; ++r) { p0[r] = exp2f(sa0[r]); p1[r] = exp2f(sa1[r]); }
#pragma unroll
      for (int ks = 0; ks < 2; ++ks) {
        const int rb = ks * 8;
        {
          unsigned a0 = cvtpk_bf16(p0[rb + 0], p0[rb + 1]);
          unsigned a1 = cvtpk_bf16(p0[rb + 2], p0[rb + 3]);
          unsigned b0 = cvtpk_bf16(p0[rb + 4], p0[rb + 5]);
          unsigned b1 = cvtpk_bf16(p0[rb + 6], p0[rb + 7]);
          plswap(a0, b0); plswap(a1, b1);
          union { unsigned u[4]; s16x8 v; } t;
          t.u[0] = a0; t.u[1] = a1; t.u[2] = b0; t.u[3] = b1;
          pa[0][k2 * 2 + ks] = t.v;
        }
        {
          unsigned a0 = cvtpk_bf16(p1[rb + 0], p1[rb + 1]);
          unsigned a1 = cvtpk_bf16(p1[rb + 2], p1[rb + 3]);
          unsigned b0 = cvtpk_bf16(p1[rb + 4], p1[rb + 5]);
          unsigned b1 = cvtpk_bf16(p1[rb + 6], p1[rb + 7]);
          plswap(a0, b0); plswap(a1, b1);
          union { unsigned u[4]; s16x8 v; } t;
          t.u[0] = a0; t.u[1] = a1; t.u[2] = b0; t.u[3] = b1;
          pa[1][k2 * 2 + ks] = t.v;
        }
      }
    }

    // PV + l: V fragments read once, shared by both streams (6 MFMA chains)
    __builtin_amdgcn_s_setprio(1);
#pragma unroll
    for (int ks2 = 0; ks2 < 4; ++ks2) {
      const int cb = ks2 * 32 + hi * 16;
      const int rv0 = l31, rv1 = 32 + l31;
      const s16x8 vb0 = *(const s16x8*)(pV + rv0 * 128 + (cb ^ ((rv0 & 7) << 4)));
      const s16x8 vb1 = *(const s16x8*)(pV + rv1 * 128 + (cb ^ ((rv1 & 7) << 4)));
      o00 = __builtin_amdgcn_mfma_f32_32x32x16_bf16(pa[0][ks2], vb0, o00, 0, 0, 0);
      o01 = __builtin_amdgcn_mfma_f32_32x32x16_bf16(pa[0][ks2], vb1, o01, 0, 0, 0);
      o10 = __builtin_amdgcn_mfma_f32_32x32x16_bf16(pa[1][ks2], vb0, o10, 0, 0, 0);
      o11 = __builtin_amdgcn_mfma_f32_32x32x16_bf16(pa[1][ks2], vb1, o11, 0, 0, 0);
      la0 = __builtin_amdgcn_mfma_f32_32x32x16_bf16(pa[0][ks2], fmf[ks2], la0, 0, 0, 0);
      la1 = __builtin_amdgcn_mfma_f32_32x32x16_bf16(pa[1][ks2], fmf[ks2], la1, 0, 0, 0);
    }
    __builtin_amdgcn_s_setprio(0);

    __syncthreads();
    buf ^= 1;
  }

  // ---- 2-way key-split merge, TWO-PASS so buffers fit ----
  // po: [qh][s][half][r][lane] = 8192 floats = 32 KB (aliases sK)
  // pl: [qh][s][hi][r]         = 128 floats        (aliases sV)
  float* po = (float*)&sK[0][0][0];
  float* pl = (float*)&sV[0][0][0];

  if (kh == 0) {
#pragma unroll
    for (int half = 0; half < 2; ++half)
#pragma unroll
      for (int r = 0; r < 16; ++r) {
        po[(((qh * 2 + 0) * 2 + half) * 16 + r) * 64 + l] = (half == 0) ? o00[r] : o01[r];
        po[(((qh * 2 + 1) * 2 + half) * 16 + r) * 64 + l] = (half == 0) ? o10[r] : o11[r];
      }
    if (l31 == 0) {
#pragma unroll
      for (int r = 0; r < 16; ++r) {
        pl[((qh * 2 + 0) * 2 + hi) * 16 + r] = la0[r];
        pl[((qh * 2 + 1) * 2 + hi) * 16 + r] = la1[r];
      }
    }
  }
  __syncthreads();
  if (kh == 1) {
#pragma unroll
    for (int half = 0; half < 2; ++half)
#pragma unroll
      for (int r = 0; r < 16; ++r) {
        po[(((qh * 2 + 0) * 2 + half) * 16 + r) * 64 + l] += (half == 0) ? o00[r] : o01[r];
        po[(((qh * 2 + 1) * 2 + half) * 16 + r) * 64 + l] += (half == 0) ? o10[r] : o11[r];
      }
    if (l31 == 0) {
#pragma unroll
      for (int r = 0; r < 16; ++r) {
        pl[((qh * 2 + 0) * 2 + hi) * 16 + r] += la0[r];
        pl[((qh * 2 + 1) * 2 + hi) * 16 + r] += la1[r];
      }
    }
  }
  __syncthreads();

  // wave w outputs (qm = w&1, sm = w>>1): normalize and store
  const int qm = w & 1, sm = w >> 1;
  unsigned short* ob = attb + ((size_t)b * S_) * D_ + h * 64;
#pragma unroll
  for (int r = 0; r < 16; ++r) {
    const float ls = pl[((qm * 2 + sm) * 2 + hi) * 16 + r];
    const float inv = 1.f / ls;
    const int q = qt * 128 + qm * 64 + sm * 32 + (r & 3) + 8 * (r >> 2) + 4 * hi;
#pragma unroll
    for (int half = 0; half < 2; ++half) {
      const float ov = po[(((qm * 2 + sm) * 2 + half) * 16 + r) * 64 + l];
      ob[(size_t)q * D_ + half * 32 + l31] = f2bf(ov * inv);
    }
  }
}

// ---------------------------------------------------------------------------
// proj: out[8192,512] = attb(bf16) @ W via Wt[n][k], MFMA, 128x128 tiles.
// ---------------------------------------------------------------------------
__global__ __launch_bounds__(256) void proj_mfma_kernel(
    const unsigned short* __restrict__ A, const unsigned short* __restrict__ Wt,
    float* __restrict__ out)
{
  __shared__ unsigned short sA[128 * 64];
  __shared__ unsigned short sB[128 * 64];
  const int m0 = blockIdx.x * 128, n0 = blockIdx.y * 128;
  const int tid = threadIdx.x, w = tid >> 6, l = tid & 63;
  const int l15 = l & 15, l4 = l >> 4;
  const int wm = (w >> 1) * 64, wn = (w & 1) * 64;
  const int swl = ((l & 7) ^ (l >> 3)) * 16;
  const int r8 = l >> 3;

  f32x4 acc[4][4];
#pragma unroll
  for (int i = 0; i < 4; ++i)
#pragma unroll
    for (int j = 0; j < 4; ++j) acc[i][j] = (f32x4){0.f, 0.f, 0.f, 0.f};

  for (int kt = 0; kt < 8; ++kt) {
    const int k0 = kt * 64;
    __syncthreads();
#pragma unroll
    for (int c = 0; c < 4; ++c) {
      const int chunk = w * 4 + c;
      const int r = chunk * 8 + r8;
      gload16((const char*)(A + ((size_t)(m0 + r)) * 512 + k0) + swl,
              (char*)sA + chunk * 1024);
      gload16((const char*)(Wt + ((size_t)(n0 + r)) * 512 + k0) + swl,
              (char*)sB + chunk * 1024);
    }
    __syncthreads();
#pragma unroll
    for (int ks = 0; ks < 2; ++ks) {
      s16x8 af[4], bf_[4];
#pragma unroll
      for (int mb = 0; mb < 4; ++mb) {
        const int row = wm + mb * 16 + l15;
        const int sz = (row & 7) << 4;
        af[mb] = *(const s16x8*)((const char*)sA + row * 128 + ((ks * 64 + l4 * 16) ^ sz));
      }
#pragma unroll
      for (int nb = 0; nb < 4; ++nb) {
        const int row = wn + nb * 16 + l15;
        const int sz = (row & 7) << 4;
        bf_[nb] = *(const s16x8*)((const char*)sB + row * 128 + ((ks * 64 + l4 * 16) ^ sz));
      }
#pragma unroll
      for (int mb = 0; mb < 4; ++mb)
#pragma unroll
        for (int nb = 0; nb < 4; ++nb)
          acc[mb][nb] = __builtin_amdgcn_mfma_f32_16x16x32_bf16(af[mb], bf_[nb], acc[mb][nb], 0, 0, 0);
    }
  }
#pragma unroll
  for (int mb = 0; mb < 4; ++mb)
#pragma unroll
    for (int nb = 0; nb < 4; ++nb)
#pragma unroll
      for (int r = 0; r < 4; ++r)
        out[(size_t)(m0 + wm + mb * 16 + l4 * 4 + r) * 512 + n0 + wn + nb * 16 + l15] =
            acc[mb][nb][r];
}

extern "C" void kernel_launch(void* const* d_in, const int* in_sizes, int n_in,
                              void* d_out, int out_size, void* d_ws, size_t ws_size,
                              hipStream_t stream) {
  const float* q    = (const float*)d_in[0];
  const float* k    = (const float*)d_in[1];
  const float* v    = (const float*)d_in[2];
  const int*   mask = (const int*)d_in[3];
  const float* cut  = (const float*)d_in[4];
  const float* W    = (const float*)d_in[5];
  float* out = (float*)d_out;

  char* ws = (char*)d_ws;
  unsigned short* Kbf  = (unsigned short*)(ws);                    // 8 MB
  unsigned short* Vt   = (unsigned short*)(ws + (8u << 20));       // 8 MB
  unsigned short* attb = (unsigned short*)(ws + (16u << 20));      // 8 MB
  unsigned short* Wt   = (unsigned short*)(ws + (24u << 20));      // 0.5 MB
  unsigned short* fmg  = (unsigned short*)(ws + (25u << 20));      // 16 KB

  conv_kv_kernel<<<dim3(S_ / 64, B_ * H_), 256, 0, stream>>>(k, v, cut, mask, Kbf, Vt, fmg);
  conv_w_kernel<<<dim3(8, 8), 256, 0, stream>>>(W, Wt);
  attn_mfma_kernel<<<dim3(S_ / 128, B_ * H_), 256, 0, stream>>>(q, Kbf, Vt, fmg, attb);
  proj_mfma_kernel<<<dim3(64, 4), 256, 0, stream>>>(attb, Wt, out);
}

// Round 13
// 80.712 us; speedup vs baseline: 1.2963x; 1.1500x over previous
//
#include <hip/hip_runtime.h>
#include <hip/hip_bf16.h>
#include <stdint.h>

#define B_ 4
#define S_ 2048
#define D_ 512
#define H_ 8

typedef __attribute__((ext_vector_type(4))) float f32x4;
typedef __attribute__((ext_vector_type(16))) float f32x16;
typedef __attribute__((ext_vector_type(8))) short s16x8;

__device__ __forceinline__ unsigned short f2bf(float x) {
  union { float f; unsigned u; } v; v.f = x;
  unsigned r = v.u + 0x7FFFu + ((v.u >> 16) & 1u);
  return (unsigned short)(r >> 16);
}

__device__ __forceinline__ unsigned cvtpk_bf16(float lo, float hi) {
  unsigned r;
  asm("v_cvt_pk_bf16_f32 %0, %1, %2" : "=v"(r) : "v"(lo), "v"(hi));
  return r;
}

// v_permlane32_swap_b32: a <- {a.lo, b.lo}, b <- {a.hi, b.hi}
__device__ __forceinline__ void plswap(unsigned &a, unsigned &b) {
  asm("v_permlane32_swap_b32 %0, %1" : "+v"(a), "+v"(b));
}

__device__ __forceinline__ void gload16(const void* g, void* lds) {
  __builtin_amdgcn_global_load_lds(
      (const __attribute__((address_space(1))) void*)g,
      (__attribute__((address_space(3))) void*)lds, 16, 0, 0);
}

// ---------------------------------------------------------------------------
// conv_kv: Kbf[bh][s][dh] = bf16(K); Vt[bh][dh][s] = bf16(V * cutoff * mask);
// fmgf[b][s] = mask ? 1.0f : 0.0f.  grid (S/64, B*H), 256 threads.
// ---------------------------------------------------------------------------
__global__ __launch_bounds__(256) void conv_kv_kernel(
    const float* __restrict__ km, const float* __restrict__ vm,
    const float* __restrict__ cut, const int* __restrict__ mask,
    unsigned short* __restrict__ Kbf, unsigned short* __restrict__ Vt,
    float* __restrict__ fmgf)
{
  const int st = blockIdx.x, bh = blockIdx.y;
  const int b = bh >> 3, h = bh & 7;
  const int s0 = st * 64;
  __shared__ unsigned short sT[64][68];
  const int tid = threadIdx.x;
#pragma unroll
  for (int j = 0; j < 4; ++j) {
    const int li = tid + j * 256;
    const int r  = li >> 4;
    const int c4 = (li & 15) * 4;
    const size_t g = ((size_t)(b * S_ + s0 + r)) * D_ + h * 64 + c4;
    const float4 kv = *(const float4*)(km + g);
    const float4 vv = *(const float4*)(vm + g);
    const int mk = mask[(size_t)b * S_ + s0 + r];
    const float f = mk ? cut[(size_t)b * S_ + s0 + r] : 0.f;
    *(ushort4*)(Kbf + ((size_t)(bh * S_ + s0 + r)) * 64 + c4) =
        make_ushort4(f2bf(kv.x), f2bf(kv.y), f2bf(kv.z), f2bf(kv.w));
    sT[r][c4 + 0] = f2bf(vv.x * f);
    sT[r][c4 + 1] = f2bf(vv.y * f);
    sT[r][c4 + 2] = f2bf(vv.z * f);
    sT[r][c4 + 3] = f2bf(vv.w * f);
    if (h == 0 && c4 == 0)
      fmgf[(size_t)b * S_ + s0 + r] = mk ? 1.0f : 0.0f;
  }
  __syncthreads();
#pragma unroll
  for (int j = 0; j < 4; ++j) {
    const int li = tid + j * 256;
    const int dh = li >> 4;
    const int s4 = (li & 15) * 4;
    *(ushort4*)(Vt + ((size_t)(bh * 64 + dh)) * S_ + s0 + s4) =
        make_ushort4(sT[s4 + 0][dh], sT[s4 + 1][dh], sT[s4 + 2][dh], sT[s4 + 3][dh]);
  }
}

// ---------------------------------------------------------------------------
// conv_w: Wt[n][k] = bf16(W[k][n]).  grid (8, 8), 256 threads
// ---------------------------------------------------------------------------
__global__ __launch_bounds__(256) void conv_w_kernel(
    const float* __restrict__ W, unsigned short* __restrict__ Wt)
{
  const int k0 = blockIdx.x * 64, n0 = blockIdx.y * 64;
  __shared__ unsigned short sT[64][68];
  const int tid = threadIdx.x;
#pragma unroll
  for (int j = 0; j < 4; ++j) {
    const int li = tid + j * 256;
    const int r  = li >> 4;
    const int c4 = (li & 15) * 4;
    const float4 wv = *(const float4*)(W + (size_t)(k0 + r) * 512 + n0 + c4);
    sT[r][c4 + 0] = f2bf(wv.x);
    sT[r][c4 + 1] = f2bf(wv.y);
    sT[r][c4 + 2] = f2bf(wv.z);
    sT[r][c4 + 3] = f2bf(wv.w);
  }
  __syncthreads();
#pragma unroll
  for (int j = 0; j < 4; ++j) {
    const int li = tid + j * 256;
    const int n  = li >> 4;
    const int k4 = (li & 15) * 4;
    *(ushort4*)(Wt + (size_t)(n0 + n) * 512 + k0 + k4) =
        make_ushort4(sT[k4 + 0][n], sT[k4 + 1][n], sT[k4 + 2][n], sT[k4 + 3][n]);
  }
}

// ---------------------------------------------------------------------------
// attn: round-12 GREEN base (r5 structure) + two asm-free deltas:
// (1) p = __builtin_amdgcn_exp2f(s)  — single v_exp_f32, compiler-managed
//     hazards (root cause of r6-r11 failures was inline-asm v_exp_f32);
// (2) denominator via VALU fmac against f32 mask (la-MFMAs removed).
// grid (S/128, B*H), 256 threads = 4 waves. Wave w = (qh = w&1, kh = w>>1):
// owns 64 q-rows (2 MFMA streams) and 1024 keys (16 tiles of 64).
// Additive (O,l) partials merged 2-way through LDS in TWO PASSES.
// ---------------------------------------------------------------------------
__global__ __launch_bounds__(256, 2) void attn_mfma_kernel(
    const float* __restrict__ qv, const unsigned short* __restrict__ Kbf,
    const unsigned short* __restrict__ Vt, const float* __restrict__ fmgf,
    unsigned short* __restrict__ attb)
{
  __shared__ unsigned short sK[2][2][4096];   // [kh][buf][key][dh] swizzled, 32 KB
  __shared__ unsigned short sV[2][2][4096];   // [kh][buf][dh][key] swizzled, 32 KB

  const int qt = blockIdx.x, bh = blockIdx.y;
  const int b = bh >> 3, h = bh & 7;
  const int tid = threadIdx.x, w = tid >> 6, l = tid & 63;
  const int l31 = l & 31, hi = l >> 5;
  const int qh = w & 1, kh = w >> 1;
  const int kbase = kh * 1024;

  // Q B-fragments, 2 streams of 32 q-rows, 1/8 * log2(e) folded in
  s16x8 qf[2][4];
#pragma unroll
  for (int s = 0; s < 2; ++s) {
    const float QS = 0.125f * 1.44269504088896f;
    const int qrow = qt * 128 + qh * 64 + s * 32 + l31;
    const float* qp = qv + ((size_t)(b * S_ + qrow)) * D_ + h * 64 + hi * 8;
#pragma unroll
    for (int kc = 0; kc < 4; ++kc) {
      const float4 a0 = *(const float4*)(qp + kc * 16);
      const float4 a1 = *(const float4*)(qp + kc * 16 + 4);
      union { unsigned u[4]; s16x8 v; } t;
      t.u[0] = cvtpk_bf16(a0.x * QS, a0.y * QS);
      t.u[1] = cvtpk_bf16(a0.z * QS, a0.w * QS);
      t.u[2] = cvtpk_bf16(a1.x * QS, a1.y * QS);
      t.u[3] = cvtpk_bf16(a1.z * QS, a1.w * QS);
      qf[s][kc] = t.v;
    }
  }

  f32x16 o00, o01, o10, o11;
  float lsum0 = 0.f, lsum1 = 0.f;
#pragma unroll
  for (int r = 0; r < 16; ++r) {
    o00[r] = 0.f; o01[r] = 0.f; o10[r] = 0.f; o11[r] = 0.f;
  }

  const int swl = ((l & 7) ^ (l >> 3)) * 16;
  const int r8  = l >> 3;
  const char* KbfB = (const char*)(Kbf + (size_t)bh * S_ * 64);
  const char* VtB  = (const char*)(Vt + (size_t)bh * 64 * S_);
  const float* fmB = fmgf + (size_t)b * S_;

  auto STAGE = [&](int bufi, int kt) {
    const int k0 = kbase + kt * 64;
#pragma unroll
    for (int c = 0; c < 4; ++c) {
      const int chunk = qh * 4 + c;          // pair {qh=0,qh=1} covers chunks 0..7
      const int row = chunk * 8 + r8;
      gload16(KbfB + (size_t)(k0 + row) * 128 + swl, (char*)sK[kh][bufi] + chunk * 1024);
      gload16(VtB + ((size_t)row * S_ + k0) * 2 + swl, (char*)sV[kh][bufi] + chunk * 1024);
    }
  };

  STAGE(0, 0);
  __syncthreads();

  int buf = 0;
  for (int kt = 0; kt < 16; ++kt) {
    const int k0 = kbase + kt * 64;
    if (kt + 1 < 16) STAGE(buf ^ 1, kt + 1);

    const char* pK = (const char*)sK[kh][buf];
    const char* pV = (const char*)sV[kh][buf];

    // QK^T per 32-key half; p = exp2(s); lsum via VALU fmac; pack A-frags
    s16x8 pa[2][4];
#pragma unroll
    for (int k2 = 0; k2 < 2; ++k2) {
      float4 fm4[4];
#pragma unroll
      for (int j = 0; j < 4; ++j)
        fm4[j] = *(const float4*)(fmB + k0 + k2 * 32 + j * 8 + hi * 4);

      f32x16 sa0, sa1;
#pragma unroll
      for (int r = 0; r < 16; ++r) { sa0[r] = 0.f; sa1[r] = 0.f; }
      __builtin_amdgcn_s_setprio(1);
#pragma unroll
      for (int kc = 0; kc < 4; ++kc) {
        const int row = k2 * 32 + l31;
        const s16x8 kf = *(const s16x8*)(pK + row * 128 +
                          ((kc * 32 + hi * 16) ^ ((row & 7) << 4)));
        sa0 = __builtin_amdgcn_mfma_f32_32x32x16_bf16(kf, qf[0][kc], sa0, 0, 0, 0);
        sa1 = __builtin_amdgcn_mfma_f32_32x32x16_bf16(kf, qf[1][kc], sa1, 0, 0, 0);
      }
      __builtin_amdgcn_s_setprio(0);

      float p0[16], p1[16];
#pragma unroll
      for (int r = 0; r < 16; ++r) {
        p0[r] = __builtin_amdgcn_exp2f(sa0[r]);
        p1[r] = __builtin_amdgcn_exp2f(sa1[r]);
      }
      // l += p . mask   (D row of reg r = (r&3) + 8*(r>>2) + 4*hi)
#pragma unroll
      for (int j = 0; j < 4; ++j) {
        lsum0 = fmaf(p0[j * 4 + 0], fm4[j].x, lsum0);
        lsum0 = fmaf(p0[j * 4 + 1], fm4[j].y, lsum0);
        lsum0 = fmaf(p0[j * 4 + 2], fm4[j].z, lsum0);
        lsum0 = fmaf(p0[j * 4 + 3], fm4[j].w, lsum0);
        lsum1 = fmaf(p1[j * 4 + 0], fm4[j].x, lsum1);
        lsum1 = fmaf(p1[j * 4 + 1], fm4[j].y, lsum1);
        lsum1 = fmaf(p1[j * 4 + 2], fm4[j].z, lsum1);
        lsum1 = fmaf(p1[j * 4 + 3], fm4[j].w, lsum1);
      }
#pragma unroll
      for (int ks = 0; ks < 2; ++ks) {
        const int rb = ks * 8;
        {
          unsigned a0 = cvtpk_bf16(p0[rb + 0], p0[rb + 1]);
          unsigned a1 = cvtpk_bf16(p0[rb + 2], p0[rb + 3]);
          unsigned b0 = cvtpk_bf16(p0[rb + 4], p0[rb + 5]);
          unsigned b1 = cvtpk_bf16(p0[rb + 6], p0[rb + 7]);
          plswap(a0, b0); plswap(a1, b1);
          union { unsigned u[4]; s16x8 v; } t;
          t.u[0] = a0; t.u[1] = a1; t.u[2] = b0; t.u[3] = b1;
          pa[0][k2 * 2 + ks] = t.v;
        }
        {
          unsigned a0 = cvtpk_bf16(p1[rb + 0], p1[rb + 1]);
          unsigned a1 = cvtpk_bf16(p1[rb + 2], p1[rb + 3]);
          unsigned b0 = cvtpk_bf16(p1[rb + 4], p1[rb + 5]);
          unsigned b1 = cvtpk_bf16(p1[rb + 6], p1[rb + 7]);
          plswap(a0, b0); plswap(a1, b1);
          union { unsigned u[4]; s16x8 v; } t;
          t.u[0] = a0; t.u[1] = a1; t.u[2] = b0; t.u[3] = b1;
          pa[1][k2 * 2 + ks] = t.v;
        }
      }
    }

    // PV: V fragments read once, shared by both streams (4 MFMA chains)
    __builtin_amdgcn_s_setprio(1);
#pragma unroll
    for (int ks2 = 0; ks2 < 4; ++ks2) {
      const int cb = ks2 * 32 + hi * 16;
      const int rv0 = l31, rv1 = 32 + l31;
      const s16x8 vb0 = *(const s16x8*)(pV + rv0 * 128 + (cb ^ ((rv0 & 7) << 4)));
      const s16x8 vb1 = *(const s16x8*)(pV + rv1 * 128 + (cb ^ ((rv1 & 7) << 4)));
      o00 = __builtin_amdgcn_mfma_f32_32x32x16_bf16(pa[0][ks2], vb0, o00, 0, 0, 0);
      o01 = __builtin_amdgcn_mfma_f32_32x32x16_bf16(pa[0][ks2], vb1, o01, 0, 0, 0);
      o10 = __builtin_amdgcn_mfma_f32_32x32x16_bf16(pa[1][ks2], vb0, o10, 0, 0, 0);
      o11 = __builtin_amdgcn_mfma_f32_32x32x16_bf16(pa[1][ks2], vb1, o11, 0, 0, 0);
    }
    __builtin_amdgcn_s_setprio(0);

    __syncthreads();
    buf ^= 1;
  }

  // total l per query (both hi halves hold complementary key subsets)
  const float lt0 = lsum0 + __shfl_xor(lsum0, 32);
  const float lt1 = lsum1 + __shfl_xor(lsum1, 32);

  // ---- 2-way kh merge through LDS, TWO-PASS ----
  // po: [qh][s][half][r][lane] = 8192 floats = 32 KB (aliases sK)
  // pl: [qh][s][q32]           = 128 floats        (aliases sV)
  float* po = (float*)&sK[0][0][0];
  float* pl = (float*)&sV[0][0][0];

  if (kh == 0) {
#pragma unroll
    for (int half = 0; half < 2; ++half)
#pragma unroll
      for (int r = 0; r < 16; ++r) {
        po[(((qh * 2 + 0) * 2 + half) * 16 + r) * 64 + l] = (half == 0) ? o00[r] : o01[r];
        po[(((qh * 2 + 1) * 2 + half) * 16 + r) * 64 + l] = (half == 0) ? o10[r] : o11[r];
      }
    if (hi == 0) {
      pl[(qh * 2 + 0) * 32 + l31] = lt0;
      pl[(qh * 2 + 1) * 32 + l31] = lt1;
    }
  }
  __syncthreads();
  if (kh == 1) {
#pragma unroll
    for (int half = 0; half < 2; ++half)
#pragma unroll
      for (int r = 0; r < 16; ++r) {
        po[(((qh * 2 + 0) * 2 + half) * 16 + r) * 64 + l] += (half == 0) ? o00[r] : o01[r];
        po[(((qh * 2 + 1) * 2 + half) * 16 + r) * 64 + l] += (half == 0) ? o10[r] : o11[r];
      }
    if (hi == 0) {
      pl[(qh * 2 + 0) * 32 + l31] += lt0;
      pl[(qh * 2 + 1) * 32 + l31] += lt1;
    }
  }
  __syncthreads();

  // wave w outputs (qm = w&1, sm = w>>1): normalize and store
  const int qm = w & 1, sm = w >> 1;
  unsigned short* ob = attb + ((size_t)b * S_) * D_ + h * 64;
#pragma unroll
  for (int r = 0; r < 16; ++r) {
    const int qloc = (r & 3) + 8 * (r >> 2) + 4 * hi;
    const float inv = 1.f / pl[(qm * 2 + sm) * 32 + qloc];
    const int q = qt * 128 + qm * 64 + sm * 32 + qloc;
#pragma unroll
    for (int half = 0; half < 2; ++half) {
      const float ov = po[(((qm * 2 + sm) * 2 + half) * 16 + r) * 64 + l];
      ob[(size_t)q * D_ + half * 32 + l31] = f2bf(ov * inv);
    }
  }
}

// ---------------------------------------------------------------------------
// proj: out[8192,512] = attb(bf16) @ W via Wt[n][k], MFMA, 128x128 tiles.
// ---------------------------------------------------------------------------
__global__ __launch_bounds__(256) void proj_mfma_kernel(
    const unsigned short* __restrict__ A, const unsigned short* __restrict__ Wt,
    float* __restrict__ out)
{
  __shared__ unsigned short sA[128 * 64];
  __shared__ unsigned short sB[128 * 64];
  const int m0 = blockIdx.x * 128, n0 = blockIdx.y * 128;
  const int tid = threadIdx.x, w = tid >> 6, l = tid & 63;
  const int l15 = l & 15, l4 = l >> 4;
  const int wm = (w >> 1) * 64, wn = (w & 1) * 64;
  const int swl = ((l & 7) ^ (l >> 3)) * 16;
  const int r8 = l >> 3;

  f32x4 acc[4][4];
#pragma unroll
  for (int i = 0; i < 4; ++i)
#pragma unroll
    for (int j = 0; j < 4; ++j) acc[i][j] = (f32x4){0.f, 0.f, 0.f, 0.f};

  for (int kt = 0; kt < 8; ++kt) {
    const int k0 = kt * 64;
    __syncthreads();
#pragma unroll
    for (int c = 0; c < 4; ++c) {
      const int chunk = w * 4 + c;
      const int r = chunk * 8 + r8;
      gload16((const char*)(A + ((size_t)(m0 + r)) * 512 + k0) + swl,
              (char*)sA + chunk * 1024);
      gload16((const char*)(Wt + ((size_t)(n0 + r)) * 512 + k0) + swl,
              (char*)sB + chunk * 1024);
    }
    __syncthreads();
#pragma unroll
    for (int ks = 0; ks < 2; ++ks) {
      s16x8 af[4], bf_[4];
#pragma unroll
      for (int mb = 0; mb < 4; ++mb) {
        const int row = wm + mb * 16 + l15;
        const int sz = (row & 7) << 4;
        af[mb] = *(const s16x8*)((const char*)sA + row * 128 + ((ks * 64 + l4 * 16) ^ sz));
      }
#pragma unroll
      for (int nb = 0; nb < 4; ++nb) {
        const int row = wn + nb * 16 + l15;
        const int sz = (row & 7) << 4;
        bf_[nb] = *(const s16x8*)((const char*)sB + row * 128 + ((ks * 64 + l4 * 16) ^ sz));
      }
#pragma unroll
      for (int mb = 0; mb < 4; ++mb)
#pragma unroll
        for (int nb = 0; nb < 4; ++nb)
          acc[mb][nb] = __builtin_amdgcn_mfma_f32_16x16x32_bf16(af[mb], bf_[nb], acc[mb][nb], 0, 0, 0);
    }
  }
#pragma unroll
  for (int mb = 0; mb < 4; ++mb)
#pragma unroll
    for (int nb = 0; nb < 4; ++nb)
#pragma unroll
      for (int r = 0; r < 4; ++r)
        out[(size_t)(m0 + wm + mb * 16 + l4 * 4 + r) * 512 + n0 + wn + nb * 16 + l15] =
            acc[mb][nb][r];
}

extern "C" void kernel_launch(void* const* d_in, const int* in_sizes, int n_in,
                              void* d_out, int out_size, void* d_ws, size_t ws_size,
                              hipStream_t stream) {
  const float* q    = (const float*)d_in[0];
  const float* k    = (const float*)d_in[1];
  const float* v    = (const float*)d_in[2];
  const int*   mask = (const int*)d_in[3];
  const float* cut  = (const float*)d_in[4];
  const float* W    = (const float*)d_in[5];
  float* out = (float*)d_out;

  char* ws = (char*)d_ws;
  unsigned short* Kbf  = (unsigned short*)(ws);                    // 8 MB
  unsigned short* Vt   = (unsigned short*)(ws + (8u << 20));       // 8 MB
  unsigned short* attb = (unsigned short*)(ws + (16u << 20));      // 8 MB
  unsigned short* Wt   = (unsigned short*)(ws + (24u << 20));      // 0.5 MB
  float*          fmgf = (float*)(ws + (25u << 20));               // 32 KB

  conv_kv_kernel<<<dim3(S_ / 64, B_ * H_), 256, 0, stream>>>(k, v, cut, mask, Kbf, Vt, fmgf);
  conv_w_kernel<<<dim3(8, 8), 256, 0, stream>>>(W, Wt);
  attn_mfma_kernel<<<dim3(S_ / 128, B_ * H_), 256, 0, stream>>>(q, Kbf, Vt, fmgf, attb);
  proj_mfma_kernel<<<dim3(64, 4), 256, 0, stream>>>(attb, Wt, out);
}